// Round 14
// baseline (236.384 us; speedup 1.0000x reference)
//
#include <hip/hip_runtime.h>
#include <hip/hip_bf16.h>

#define B_N 16
#define LP_N 1024
#define LQ_N 1024
#define H_N 1024

typedef unsigned short u16;
typedef __attribute__((ext_vector_type(8))) _Float16 f16x8;
typedef __attribute__((ext_vector_type(4))) float f32x4;

__device__ __forceinline__ u16 f2h(float x) {
    _Float16 h = (_Float16)x;
    return *(u16*)&h;
}
__device__ __forceinline__ float h2f(u16 u) {
    _Float16 h;
    *(u16*)&h = u;
    return (float)h;
}

__device__ __forceinline__ void load_lds16(const u16* g, u16* l) {
    __builtin_amdgcn_global_load_lds(
        (const __attribute__((address_space(1))) void*)g,
        (__attribute__((address_space(3))) void*)l, 16, 0, 0);
}

#define MFMA_F16(a, b, c) __builtin_amdgcn_mfma_f32_16x16x32_f16(a, b, c, 0, 0, 0)
#define VMW0()  asm volatile("s_waitcnt vmcnt(0)" ::: "memory")
#define LGKM8() asm volatile("s_waitcnt lgkmcnt(8)" ::: "memory")
#define LGKM0() asm volatile("s_waitcnt lgkmcnt(0)" ::: "memory")
#define SCHB()  __builtin_amdgcn_sched_barrier(0)
#define SBAR()  __builtin_amdgcn_s_barrier()

// ---------------------------------------------------------------------------
// BM=256 x BN_{256,128} fp16 MFMA GEMM, NT form (R14).
// R13 post-mortem: dense GEMMs (half the MFMA work) take the SAME 67us as
// the split one -> ~75% of dense tile time is gate/barrier overhead, because
// grid=256 = exactly 1 block/CU (nothing overlaps the stall; R11 failed
// because 256-thr x 2 blocks kept waves/CU at 8 - not a real occupancy move).
// R14: dense GEMMs re-tiled to BN=128 (per-wave 128x32, acc 64 VGPR, fits
// the (512,4) 128-VGPR cap), LDS dbuf 48KB -> 2 blocks/CU, grid 512 ->
// cross-block overlap of gate/LDS phases (m114). GEMM1 keeps BN=256 split
// (BN=128 split would need ~136 data VGPR -> spill at the 4-wave cap).
// Numerics (R13, verified absmax 0.0742):
//   GEMM1: keys = (q_hi + q_lo) @ W_f16      -> 2 MFMA terms
//   GEMM2: scores = p_f16 @ keys_f16^T       -> 1 term
//   GEMM3: out = relu(attn_f16 @ q_f16)      -> 1 term
// Schedule/swizzle unchanged (R9-verified, 0 conflicts): one vmcnt(0)+
// s_barrier per BK=32 tile; t+1 staged right after front ds_reads;
// 16B slot s_phys = s_log ^ ((row>>1)&3) on pre-swizzled global source AND
// frag ds_read offsets (rule #21); lgkm waits per rule #18.
// EPI: 0=fp32 store, 1=+bias fp16 store, 2=relu fp32 store.
// ---------------------------------------------------------------------------
template<int BN_, bool SPLIT, int EPI>
__launch_bounds__(512, (BN_ == 128) ? 4 : 2)
__global__ void gemm2t(const u16* __restrict__ Ahi, const u16* __restrict__ Alo,
                       const u16* __restrict__ Bm,
                       const float* __restrict__ bias,
                       float* __restrict__ Cf, u16* __restrict__ Ch,
                       int N, int gn, int gmn,
                       long long sA, long long sB, long long sC)
{
    constexpr int REG_A = 8192;                  // 256 rows x 32 cols (16KB)
    constexpr int REG_B = BN_ * 32;              // 8192 (BN=256) / 4096 (BN=128)
    constexpr int O_AL  = REG_A;                 // split only
    constexpr int O_B   = SPLIT ? 2 * REG_A : REG_A;
    constexpr int BUF   = O_B + REG_B;
    constexpr int NFRB  = BN_ / 64;              // B frags per wave (4 / 2)
    constexpr int WN    = BN_ / 4;               // per-wave N span (64 / 32)
    __shared__ __align__(16) u16 lds[2 * BUF];

    const int tid  = threadIdx.x;
    const int lane = tid & 63;
    const int wv   = tid >> 6;
    const int wr   = wv >> 2, wc = wv & 3;       // 2M x 4N waves

    // XCD-contiguous block swizzle
    const int d   = blockIdx.x;
    const int cpx = gridDim.x >> 3;
    const int swz = (d & 7) * cpx + (d >> 3);
    const long long z = swz / gmn;
    const int r_  = swz % gmn;
    const int bm  = (r_ / gn) * 256;
    const int bn  = (r_ % gn) * BN_;

    const char* pAh = (const char*)(Ahi + z * sA);
    const char* pAl = (const char*)(Alo + z * sA);
    const char* pB  = (const char*)(Bm + z * sB);

    // ---- staging: A = 1024 chunks (rows 0..255 x 4 slots), thread t stages
    // chunks {t, t+512} (rows r0, r0+128; same XOR). B = BN_*4 chunks; for
    // BN=256 same {t, t+512}; for BN=128 thread t stages chunk t only
    // (rows 0..127 = r0). chunk c: row=c>>2, phys slot=c&3,
    // src logical slot=(c&3)^((row>>1)&3). Row stride = 2048B.
    const int r0 = tid >> 2;                     // 0..127
    const int xc = (tid & 3) ^ ((r0 >> 1) & 3);
    const long long aof = (long long)(bm + r0) * 2048 + xc * 16;
    const long long bof = (long long)(bn + r0) * 2048 + xc * 16;
    const long long ao2 = aof + 128 * 2048;
    const long long bo2 = bof + 128 * 2048;      // BN=256 only
    const int d0 = tid * 8;                      // u16 dest offset (chunk t)
    const int d1 = d0 + 4096;                    // chunk t+512

    // ---- fragment ds_read offsets (u16 units within region), same swizzle
    int offA[8], offB[NFRB];
#pragma unroll
    for (int i = 0; i < 8; ++i) {
        const int r = wr * 128 + i * 16 + (lane & 15);
        offA[i] = r * 32 + ((((lane >> 4) ^ (r >> 1)) & 3) << 3);
    }
#pragma unroll
    for (int j = 0; j < NFRB; ++j) {
        const int r = wc * WN + j * 16 + (lane & 15);
        offB[j] = r * 32 + ((((lane >> 4) ^ (r >> 1)) & 3) << 3);
    }

    f32x4 acc[8][NFRB];
#pragma unroll
    for (int i = 0; i < 8; ++i)
#pragma unroll
        for (int j = 0; j < NFRB; ++j)
            acc[i][j] = (f32x4){0.f, 0.f, 0.f, 0.f};

#define STG(NB, KB) do {                                                      \
        load_lds16((const u16*)(pAh + aof + (KB)), lds + (NB) + d0);          \
        load_lds16((const u16*)(pAh + ao2 + (KB)), lds + (NB) + d1);          \
        load_lds16((const u16*)(pB + bof + (KB)), lds + (NB) + O_B + d0);     \
        if constexpr (BN_ == 256)                                             \
            load_lds16((const u16*)(pB + bo2 + (KB)), lds + (NB) + O_B + d1); \
        if constexpr (SPLIT) {                                                \
            load_lds16((const u16*)(pAl + aof + (KB)), lds + (NB) + O_AL + d0); \
            load_lds16((const u16*)(pAl + ao2 + (KB)), lds + (NB) + O_AL + d1); \
        }                                                                     \
    } while (0)

#define TERM(AF, BF) do {                                                     \
        __builtin_amdgcn_s_setprio(1);                                        \
        _Pragma("unroll")                                                     \
        for (int i = 0; i < 8; ++i)                                           \
            _Pragma("unroll")                                                 \
            for (int j = 0; j < NFRB; ++j)                                    \
                acc[i][j] = MFMA_F16(AF[i], BF[j], acc[i][j]);                \
        __builtin_amdgcn_s_setprio(0);                                        \
    } while (0)

    constexpr int NT = 32;                       // K=1024 / BK=32

    STG(0, 0);                                   // prologue: tile 0 -> buf 0

    for (int t = 0; t < NT; ++t) {
        const int cb = (t & 1) ? BUF : 0;
        const int nb = (t & 1) ? 0 : BUF;
        const long long kb = (long long)(t + 1) * 64;  // bytes

        VMW0();                  // tile t staged loads retired (per wave)
        SBAR();                  // cross-wave publish
        f16x8 b[NFRB], ah[8], al[8];
#pragma unroll
        for (int j = 0; j < NFRB; ++j)
            b[j] = *(const f16x8*)(lds + cb + O_B + offB[j]);
#pragma unroll
        for (int i = 0; i < 8; ++i)
            ah[i] = *(const f16x8*)(lds + cb + offA[i]);
        if constexpr (SPLIT) {
#pragma unroll
            for (int i = 0; i < 8; ++i)
                al[i] = *(const f16x8*)(lds + cb + O_AL + offA[i]);
        }
        if (t + 1 < NT) STG(nb, kb);             // issue t+1 early (max slack)
        if constexpr (SPLIT) { LGKM8(); } else { LGKM0(); }
        SCHB();
        TERM(ah, b);                             // T1 (al in flight if split)
        if constexpr (SPLIT) {
            LGKM0(); SCHB();
            TERM(al, b);                         // T2
        }
    }
#undef STG
#undef TERM

    // epilogue; C/D map: col = lane&15, row = (lane>>4)*4 + e  [m89/m91]
    const long long Cbase = z * sC;
#pragma unroll
    for (int i = 0; i < 8; ++i) {
        const int row0 = bm + wr * 128 + i * 16 + ((lane >> 4) << 2);
#pragma unroll
        for (int j = 0; j < NFRB; ++j) {
            const int col = bn + wc * WN + j * 16 + (lane & 15);
#pragma unroll
            for (int e = 0; e < 4; ++e) {
                const float v = acc[i][j][e];
                const long long idx = Cbase + (long long)(row0 + e) * N + col;
                if constexpr (EPI == 0) {
                    Cf[idx] = v;
                } else if constexpr (EPI == 1) {
                    Ch[idx] = f2h(v + bias[col]);
                } else {
                    Cf[idx] = fmaxf(v, 0.f);
                }
            }
        }
    }
}

// fp32 -> fp16 single, 4 elems/thread (p pre-pass)
__global__ void cvt_f16(const float* __restrict__ in, u16* __restrict__ o16,
                        long long n4)
{
    const long long i = (long long)blockIdx.x * 256 + threadIdx.x;
    if (i >= n4) return;
    const float4 v = ((const float4*)in)[i];
    ushort4 h;
    h.x = f2h(v.x); h.y = f2h(v.y); h.z = f2h(v.z); h.w = f2h(v.w);
    ((ushort4*)o16)[i] = h;
}

// fused q pre-pass: read q once per 32x32 tile -> q_hi, q_lo (straight, fp16)
// and qT (transposed, fp16 single for GEMM3's B).
__global__ void fuse_cvt_q(const float* __restrict__ q, u16* __restrict__ hi,
                           u16* __restrict__ lo, u16* __restrict__ thi)
{
    __shared__ float t[32][33];
    const long long z = blockIdx.z;
    const long long base = z * 1048576;
    const int r0 = blockIdx.y * 32, c0 = blockIdx.x * 32;
    for (int j = threadIdx.y; j < 32; j += 8) {
        const float v = q[base + (long long)(r0 + j) * 1024 + c0 + threadIdx.x];
        t[j][threadIdx.x] = v;
        const long long o = base + (long long)(r0 + j) * 1024 + c0 + threadIdx.x;
        const u16 h = f2h(v);
        hi[o] = h;
        lo[o] = f2h(v - h2f(h));
    }
    __syncthreads();
    for (int j = threadIdx.y; j < 32; j += 8)
        thi[base + (long long)(c0 + j) * 1024 + r0 + threadIdx.x] = f2h(t[threadIdx.x][j]);
}

// Wt[c][r] = W[r][c], fp16 single (W pre-pass; W rounding error negligible)
__global__ void transpose_cvt_w(const float* __restrict__ in, u16* __restrict__ hi)
{
    __shared__ float t[32][33];
    const int r0 = blockIdx.y * 32, c0 = blockIdx.x * 32;
    for (int j = threadIdx.y; j < 32; j += 8)
        t[j][threadIdx.x] = in[(long long)(r0 + j) * 1024 + c0 + threadIdx.x];
    __syncthreads();
    for (int j = threadIdx.y; j < 32; j += 8)
        hi[(long long)(c0 + j) * 1024 + r0 + threadIdx.x] = f2h(t[threadIdx.x][j]);
}

// row softmax (fp32 in, fp16 out), one 256-thread block per 1024-elem row
__global__ void softmax_f16(const float* __restrict__ S, u16* __restrict__ A)
{
    const long long row = blockIdx.x;
    const float* r = S + row * (long long)LQ_N;
    const int t = threadIdx.x;
    float4 v = ((const float4*)r)[t];

    float m = fmaxf(fmaxf(v.x, v.y), fmaxf(v.z, v.w));
#pragma unroll
    for (int off = 32; off > 0; off >>= 1)
        m = fmaxf(m, __shfl_xor(m, off));

    __shared__ float red[4];
    const int lane = t & 63, wid = t >> 6;
    if (lane == 0) red[wid] = m;
    __syncthreads();
    m = fmaxf(fmaxf(red[0], red[1]), fmaxf(red[2], red[3]));
    __syncthreads();

    v.x = __expf(v.x - m); v.y = __expf(v.y - m);
    v.z = __expf(v.z - m); v.w = __expf(v.w - m);
    float s = v.x + v.y + v.z + v.w;
#pragma unroll
    for (int off = 32; off > 0; off >>= 1)
        s += __shfl_xor(s, off);
    if (lane == 0) red[wid] = s;
    __syncthreads();
    s = red[0] + red[1] + red[2] + red[3];

    const float inv = 1.0f / s;
    ushort4 o;
    o.x = f2h(v.x * inv); o.y = f2h(v.y * inv);
    o.z = f2h(v.z * inv); o.w = f2h(v.w * inv);
    ((ushort4*)(A + row * (long long)LQ_N))[t] = o;
}

// ---------------------------------------------------------------------------
// Fallback fp32 path (round-1, verified; needs only 128 MB ws)
// ---------------------------------------------------------------------------
#define BM 128
#define BN 128
#define BK 8
#define TM 8
#define TN 8

template<bool TRANSB, bool BIAS, bool RELU>
__launch_bounds__(256)
__global__ void gemm_k(const float* __restrict__ A, const float* __restrict__ Bmat,
                       const float* __restrict__ bias, float* __restrict__ C,
                       int M, int N, int K,
                       long long sA, long long sB, long long sC)
{
    __shared__ float As[BK][BM];
    __shared__ float Bs[BK][BN];
    const int tid = threadIdx.x;
    const int tx = tid & 15;
    const int ty = tid >> 4;
    const int bn = blockIdx.x * BN;
    const int bm = blockIdx.y * BM;
    const long long z = blockIdx.z;
    A += z * sA; Bmat += z * sB; C += z * sC;
    float acc[TM][TN];
#pragma unroll
    for (int i = 0; i < TM; i++)
#pragma unroll
        for (int j = 0; j < TN; j++) acc[i][j] = 0.f;
    const int arow = tid >> 1;
    const int acol = (tid & 1) * 4;
    const int bk_n = tid >> 5;
    const int bn_n = (tid & 31) * 4;
    for (int k0 = 0; k0 < K; k0 += BK) {
        float4 a4 = *(const float4*)&A[(long long)(bm + arow) * K + k0 + acol];
        As[acol + 0][arow] = a4.x; As[acol + 1][arow] = a4.y;
        As[acol + 2][arow] = a4.z; As[acol + 3][arow] = a4.w;
        if (TRANSB) {
            float4 b4 = *(const float4*)&Bmat[(long long)(bn + arow) * K + k0 + acol];
            Bs[acol + 0][arow] = b4.x; Bs[acol + 1][arow] = b4.y;
            Bs[acol + 2][arow] = b4.z; Bs[acol + 3][arow] = b4.w;
        } else {
            float4 b4 = *(const float4*)&Bmat[(long long)(k0 + bk_n) * N + bn + bn_n];
            *(float4*)&Bs[bk_n][bn_n] = b4;
        }
        __syncthreads();
#pragma unroll
        for (int k = 0; k < BK; k++) {
            float a[TM], b[TN];
            *(float4*)&a[0] = *(const float4*)&As[k][ty * TM];
            *(float4*)&a[4] = *(const float4*)&As[k][ty * TM + 4];
            *(float4*)&b[0] = *(const float4*)&Bs[k][tx * TN];
            *(float4*)&b[4] = *(const float4*)&Bs[k][tx * TN + 4];
#pragma unroll
            for (int i = 0; i < TM; i++)
#pragma unroll
                for (int j = 0; j < TN; j++)
                    acc[i][j] = fmaf(a[i], b[j], acc[i][j]);
        }
        __syncthreads();
    }
#pragma unroll
    for (int i = 0; i < TM; i++) {
        const int row = bm + ty * TM + i;
#pragma unroll
        for (int j = 0; j < TN; j += 4) {
            const int col = bn + tx * TN + j;
            float4 v;
            v.x = acc[i][j + 0]; v.y = acc[i][j + 1];
            v.z = acc[i][j + 2]; v.w = acc[i][j + 3];
            if (BIAS) {
                v.x += bias[col + 0]; v.y += bias[col + 1];
                v.z += bias[col + 2]; v.w += bias[col + 3];
            }
            if (RELU) {
                v.x = fmaxf(v.x, 0.f); v.y = fmaxf(v.y, 0.f);
                v.z = fmaxf(v.z, 0.f); v.w = fmaxf(v.w, 0.f);
            }
            *(float4*)&C[(long long)row * N + col] = v;
        }
    }
}

__global__ void softmax_k(float* __restrict__ S)
{
    const long long row = blockIdx.x;
    float* r = S + row * (long long)LQ_N;
    const int t = threadIdx.x;
    float4 v = ((float4*)r)[t];
    float m = fmaxf(fmaxf(v.x, v.y), fmaxf(v.z, v.w));
#pragma unroll
    for (int off = 32; off > 0; off >>= 1)
        m = fmaxf(m, __shfl_xor(m, off));
    __shared__ float red[4];
    const int lane = t & 63, wid = t >> 6;
    if (lane == 0) red[wid] = m;
    __syncthreads();
    m = fmaxf(fmaxf(red[0], red[1]), fmaxf(red[2], red[3]));
    __syncthreads();
    v.x = __expf(v.x - m); v.y = __expf(v.y - m);
    v.z = __expf(v.z - m); v.w = __expf(v.w - m);
    float s = v.x + v.y + v.z + v.w;
#pragma unroll
    for (int off = 32; off > 0; off >>= 1)
        s += __shfl_xor(s, off);
    if (lane == 0) red[wid] = s;
    __syncthreads();
    s = red[0] + red[1] + red[2] + red[3];
    const float inv = 1.0f / s;
    v.x *= inv; v.y *= inv; v.z *= inv; v.w *= inv;
    ((float4*)r)[t] = v;
}

extern "C" void kernel_launch(void* const* d_in, const int* in_sizes, int n_in,
                              void* d_out, int out_size, void* d_ws, size_t ws_size,
                              hipStream_t stream)
{
    const float* p    = (const float*)d_in[0];
    const float* q    = (const float*)d_in[1];
    const float* W    = (const float*)d_in[2];
    const float* bias = (const float*)d_in[3];
    float* out = (float*)d_out;

    const size_t MB32 = 33554432ull;                 // 16M fp16
    const size_t NEED = 5 * MB32 + 2097152ull;       // 160 MB + 2 MB

    if (ws_size >= NEED) {
        char* w = (char*)d_ws;
        u16* p16   = (u16*)(w + 0 * MB32);
        u16* q_hi  = (u16*)(w + 1 * MB32);
        u16* q_lo  = (u16*)(w + 2 * MB32);
        u16* keys  = (u16*)(w + 3 * MB32);
        u16* qT    = (u16*)(w + 4 * MB32);
        u16* Wt    = (u16*)(w + 5 * MB32);
        float* scores = (float*)(w + 1 * MB32);  // reuses q_hi/q_lo after GEMM1
        u16* attn     = (u16*)(w + 0 * MB32);    // reuses p16 after GEMM2

        const long long n4 = (long long)B_N * LQ_N * H_N / 4;
        cvt_f16<<<dim3((unsigned)(n4 / 256)), 256, 0, stream>>>(p, p16, n4);
        fuse_cvt_q<<<dim3(32, 32, B_N), dim3(32, 8), 0, stream>>>(q, q_hi, q_lo, qT);
        transpose_cvt_w<<<dim3(32, 32, 1), dim3(32, 8), 0, stream>>>(W, Wt);

        // keys = (q_hi + q_lo) @ Wt + b : 2 terms, 256x256, grid 256.
        gemm2t<256, true, 1><<<256, 512, 0, stream>>>(
            q_hi, q_lo, Wt, bias, nullptr, keys,
            H_N, /*gn=*/4, /*gmn=*/256, 0, 0, 0);

        // scores[b] = p16[b] @ keys[b]^T : dense, 256x128, grid 512 (2 blk/CU).
        gemm2t<128, false, 0><<<512, 512, 0, stream>>>(
            p16, p16, keys, nullptr, scores, nullptr,
            LQ_N, /*gn=*/8, /*gmn=*/32,
            (long long)LP_N * H_N, (long long)LQ_N * H_N, (long long)LP_N * LQ_N);

        softmax_f16<<<B_N * LP_N, 256, 0, stream>>>(scores, attn);

        // out[b] = relu(attn[b] @ q[b]) : dense, 256x128, grid 512.
        gemm2t<128, false, 2><<<512, 512, 0, stream>>>(
            attn, attn, qT, nullptr, out, nullptr,
            H_N, /*gn=*/8, /*gmn=*/32,
            (long long)LP_N * LQ_N, (long long)H_N * LQ_N, (long long)LP_N * H_N);
    } else {
        float* keys   = (float*)d_ws;
        float* scores = keys + (long long)B_N * LQ_N * H_N;

        gemm_k<false, true, false><<<dim3(H_N / BN, (B_N * LQ_N) / BM, 1), 256, 0, stream>>>(
            q, W, bias, keys, B_N * LQ_N, H_N, H_N, 0, 0, 0);
        gemm_k<true, false, false><<<dim3(LQ_N / BN, LP_N / BM, B_N), 256, 0, stream>>>(
            p, keys, nullptr, scores, LP_N, LQ_N, H_N,
            (long long)LP_N * H_N, (long long)LQ_N * H_N, (long long)LP_N * LQ_N);
        softmax_k<<<B_N * LP_N, 256, 0, stream>>>(scores);
        gemm_k<false, false, true><<<dim3(H_N / BN, LP_N / BM, B_N), 256, 0, stream>>>(
            scores, q, nullptr, out, LP_N, H_N, LQ_N,
            (long long)LP_N * LQ_N, (long long)LQ_N * H_N, (long long)LP_N * H_N);
    }
}

// Round 15
// 227.603 us; speedup vs baseline: 1.0386x; 1.0386x over previous
//
#include <hip/hip_runtime.h>
#include <hip/hip_bf16.h>

#define B_N 16
#define LP_N 1024
#define LQ_N 1024
#define H_N 1024

typedef unsigned short u16;
typedef __attribute__((ext_vector_type(8))) _Float16 f16x8;
typedef __attribute__((ext_vector_type(4))) float f32x4;

__device__ __forceinline__ u16 f2h(float x) {
    _Float16 h = (_Float16)x;
    return *(u16*)&h;
}
__device__ __forceinline__ float h2f(u16 u) {
    _Float16 h;
    *(u16*)&h = u;
    return (float)h;
}

__device__ __forceinline__ void load_lds16(const u16* g, u16* l) {
    __builtin_amdgcn_global_load_lds(
        (const __attribute__((address_space(1))) void*)g,
        (__attribute__((address_space(3))) void*)l, 16, 0, 0);
}

#define MFMA_F16(a, b, c) __builtin_amdgcn_mfma_f32_16x16x32_f16(a, b, c, 0, 0, 0)
#define VMW0()   asm volatile("s_waitcnt vmcnt(0)" ::: "memory")
#define LGKM12() asm volatile("s_waitcnt lgkmcnt(12)" ::: "memory")
#define LGKM8()  asm volatile("s_waitcnt lgkmcnt(8)" ::: "memory")
#define LGKM0()  asm volatile("s_waitcnt lgkmcnt(0)" ::: "memory")
#define SCHB()   __builtin_amdgcn_sched_barrier(0)
#define SBAR()   __builtin_amdgcn_s_barrier()

// ---------------------------------------------------------------------------
// 256x256 fp16 MFMA GEMM, NT form (R15).
// R13/R14 post-mortem: all GEMMs ~67us regardless of MFMA content -> per-
// K-tile FIXED cost (~4000cyc: gate + 2 barriers + ds-read chains + LDS-write
// drain) dominates at 32 tiles. R15: dense GEMMs go BK=64 -> 16 tiles, 2x
// the MFMA per gate (64/wave), same total LDS traffic. Dense dbuf at BK=64 =
// 2 x 32KB x 2 = 128KB (1 blk/CU, unchanged). Split GEMM1 (3 regions) can't
// dbuf at BK=64 -> stays at its proven BK=32 config.
// BK=64 swizzle: rows are 128B (span ALL 32 banks uniformly -> identical
// bank mapping every row; no R8 parity trap). 8 x 16B slots/row,
// slot_phys = slot_log ^ (row&7) on BOTH pre-swizzled global staging source
// and frag ds_read offsets (rule #21). Frag read: 16-lane group cycles the
// XOR over 8 slots -> 2 lanes/slot -> uniform 8 touches/bank = b128 floor.
// BK=32 path: R13-verified geometry (slot ^ (row>>1)&3), 0 conflicts.
// Schedule per tile: VMW0+SBAR gate; read subk0 frags (12), STG t+1, read
// subk1 frags (12); lgkmcnt(12)+SCHB -> TERM subk0 (subk1 reads in flight);
// lgkmcnt(0)+SCHB -> TERM subk1. Split (BK32): lgkm(8) T1, lgkm(0) T2.
// Numerics (R13-verified, absmax 0.0742):
//   GEMM1: keys = (q_hi + q_lo) @ W_f16  [BK32 split]
//   GEMM2: scores = p @ keys^T           [BK64 dense]
//   GEMM3: out = relu(attn @ qT)         [BK64 dense]
// EPI: 0=fp32 store, 1=+bias fp16 store, 2=relu fp32 store.
// ---------------------------------------------------------------------------
template<int BKT, bool SPLIT, int EPI>
__launch_bounds__(512, 2)
__global__ void gemm2t(const u16* __restrict__ Ahi, const u16* __restrict__ Alo,
                       const u16* __restrict__ Bm,
                       const float* __restrict__ bias,
                       float* __restrict__ Cf, u16* __restrict__ Ch,
                       int N, int gn, int gmn,
                       long long sA, long long sB, long long sC)
{
    constexpr int REG   = 256 * BKT;             // u16 per 256 x BKT region
    constexpr int O_AL  = REG;                   // split only
    constexpr int O_B   = SPLIT ? 2 * REG : REG;
    constexpr int BUF   = O_B + REG;
    constexpr int NSUBK = BKT / 32;              // 1 (BK32) / 2 (BK64)
    constexpr int CH    = BKT / 16;              // staging chunks/thread/region
    constexpr int RSTEP = 256 / CH;              // row step between chunks
    __shared__ __align__(16) u16 lds[2 * BUF];

    const int tid  = threadIdx.x;
    const int lane = tid & 63;
    const int wv   = tid >> 6;
    const int wr   = wv >> 2, wc = wv & 3;       // 2M x 4N waves

    // XCD-contiguous block swizzle
    const int d   = blockIdx.x;
    const int cpx = gridDim.x >> 3;
    const int swz = (d & 7) * cpx + (d >> 3);
    const long long z = swz / gmn;
    const int r_  = swz % gmn;
    const int bm  = (r_ / gn) * 256;
    const int bn  = (r_ % gn) * 256;

    const char* pAh = (const char*)(Ahi + z * sA);
    const char* pAl = (const char*)(Alo + z * sA);
    const char* pB  = (const char*)(Bm + z * sB);

    // ---- staging geometry. BK32: rr=tid>>2 (0..127), 4 slots,
    // xor=(rr>>1)&3 (R13-verified). BK64: rr=tid>>3 (0..63), 8 slots,
    // xor=rr&7. Chunk j covers row rr + j*RSTEP (XOR invariant: RSTEP is a
    // multiple of 8 (64/128), so (rr+j*RSTEP) low bits match rr).
    const int rr  = (BKT == 32) ? (tid >> 2) : (tid >> 3);
    const int xcv = (BKT == 32) ? ((tid & 3) ^ ((rr >> 1) & 3))
                                : ((tid & 7) ^ (rr & 7));
    long long aofs[CH], bofs[CH];
#pragma unroll
    for (int j = 0; j < CH; ++j) {
        aofs[j] = (long long)(bm + rr + j * RSTEP) * 2048 + xcv * 16;
        bofs[j] = (long long)(bn + rr + j * RSTEP) * 2048 + xcv * 16;
    }

    // ---- fragment ds_read offsets (u16 units within region)
    int offA[8][NSUBK], offB[4][NSUBK];
#pragma unroll
    for (int i = 0; i < 8; ++i) {
        const int r = wr * 128 + i * 16 + (lane & 15);
#pragma unroll
        for (int s = 0; s < NSUBK; ++s) {
            if constexpr (BKT == 32)
                offA[i][s] = r * 32 + ((((lane >> 4) ^ (r >> 1)) & 3) << 3);
            else
                offA[i][s] = r * 64 + ((((s * 4 + (lane >> 4)) ^ r) & 7) << 3);
        }
    }
#pragma unroll
    for (int j = 0; j < 4; ++j) {
        const int r = wc * 64 + j * 16 + (lane & 15);
#pragma unroll
        for (int s = 0; s < NSUBK; ++s) {
            if constexpr (BKT == 32)
                offB[j][s] = r * 32 + ((((lane >> 4) ^ (r >> 1)) & 3) << 3);
            else
                offB[j][s] = r * 64 + ((((s * 4 + (lane >> 4)) ^ r) & 7) << 3);
        }
    }

    f32x4 acc[8][4];
#pragma unroll
    for (int i = 0; i < 8; ++i)
#pragma unroll
        for (int j = 0; j < 4; ++j)
            acc[i][j] = (f32x4){0.f, 0.f, 0.f, 0.f};

#define STG(NB, KB) do {                                                      \
        _Pragma("unroll")                                                     \
        for (int j = 0; j < CH; ++j) {                                        \
            load_lds16((const u16*)(pAh + aofs[j] + (KB)),                    \
                       lds + (NB) + tid * 8 + j * 4096);                      \
            load_lds16((const u16*)(pB + bofs[j] + (KB)),                     \
                       lds + (NB) + O_B + tid * 8 + j * 4096);                \
            if constexpr (SPLIT)                                              \
                load_lds16((const u16*)(pAl + aofs[j] + (KB)),                \
                           lds + (NB) + O_AL + tid * 8 + j * 4096);           \
        }                                                                     \
    } while (0)

#define TERM(AF, BF) do {                                                     \
        __builtin_amdgcn_s_setprio(1);                                        \
        _Pragma("unroll")                                                     \
        for (int i = 0; i < 8; ++i)                                           \
            _Pragma("unroll")                                                 \
            for (int j = 0; j < 4; ++j)                                       \
                acc[i][j] = MFMA_F16(AF[i], BF[j], acc[i][j]);                \
        __builtin_amdgcn_s_setprio(0);                                        \
    } while (0)

    constexpr int NT = 1024 / BKT;

    STG(0, 0);                                   // prologue: tile 0 -> buf 0

    for (int t = 0; t < NT; ++t) {
        const int cb = (t & 1) ? BUF : 0;
        const int nb = (t & 1) ? 0 : BUF;
        const long long kb = (long long)(t + 1) * (BKT * 2);  // bytes

        VMW0();                  // tile t staged loads retired (per wave)
        SBAR();                  // cross-wave publish

        if constexpr (BKT == 32) {
            f16x8 b[4], ah[8], al[8];
#pragma unroll
            for (int j = 0; j < 4; ++j)
                b[j] = *(const f16x8*)(lds + cb + O_B + offB[j][0]);
#pragma unroll
            for (int i = 0; i < 8; ++i)
                ah[i] = *(const f16x8*)(lds + cb + offA[i][0]);
            if constexpr (SPLIT) {
#pragma unroll
                for (int i = 0; i < 8; ++i)
                    al[i] = *(const f16x8*)(lds + cb + O_AL + offA[i][0]);
            }
            if (t + 1 < NT) STG(nb, kb);
            if constexpr (SPLIT) { LGKM8(); } else { LGKM0(); }
            SCHB();
            TERM(ah, b);
            if constexpr (SPLIT) {
                LGKM0(); SCHB();
                TERM(al, b);
            }
        } else {
            // BK64 dense: subk0 reads, STG, subk1 reads; counted lgkm waits.
            f16x8 b0[4], a0[8], b1[4], a1[8];
#pragma unroll
            for (int j = 0; j < 4; ++j)
                b0[j] = *(const f16x8*)(lds + cb + O_B + offB[j][0]);
#pragma unroll
            for (int i = 0; i < 8; ++i)
                a0[i] = *(const f16x8*)(lds + cb + offA[i][0]);
            if (t + 1 < NT) STG(nb, kb);
#pragma unroll
            for (int j = 0; j < 4; ++j)
                b1[j] = *(const f16x8*)(lds + cb + O_B + offB[j][1]);
#pragma unroll
            for (int i = 0; i < 8; ++i)
                a1[i] = *(const f16x8*)(lds + cb + offA[i][1]);
            LGKM12(); SCHB();
            TERM(a0, b0);                        // subk1 reads in flight
            LGKM0(); SCHB();
            TERM(a1, b1);
        }
    }
#undef STG
#undef TERM

    // epilogue; C/D map: col = lane&15, row = (lane>>4)*4 + e  [m89/m91]
    const long long Cbase = z * sC;
#pragma unroll
    for (int i = 0; i < 8; ++i) {
        const int row0 = bm + wr * 128 + i * 16 + ((lane >> 4) << 2);
#pragma unroll
        for (int j = 0; j < 4; ++j) {
            const int col = bn + wc * 64 + j * 16 + (lane & 15);
#pragma unroll
            for (int e = 0; e < 4; ++e) {
                const float v = acc[i][j][e];
                const long long idx = Cbase + (long long)(row0 + e) * N + col;
                if constexpr (EPI == 0) {
                    Cf[idx] = v;
                } else if constexpr (EPI == 1) {
                    Ch[idx] = f2h(v + bias[col]);
                } else {
                    Cf[idx] = fmaxf(v, 0.f);
                }
            }
        }
    }
}

// fp32 -> fp16 single, 4 elems/thread (p pre-pass)
__global__ void cvt_f16(const float* __restrict__ in, u16* __restrict__ o16,
                        long long n4)
{
    const long long i = (long long)blockIdx.x * 256 + threadIdx.x;
    if (i >= n4) return;
    const float4 v = ((const float4*)in)[i];
    ushort4 h;
    h.x = f2h(v.x); h.y = f2h(v.y); h.z = f2h(v.z); h.w = f2h(v.w);
    ((ushort4*)o16)[i] = h;
}

// fused q pre-pass: read q once per 32x32 tile -> q_hi, q_lo (straight, fp16)
// and qT (transposed, fp16 single for GEMM3's B).
__global__ void fuse_cvt_q(const float* __restrict__ q, u16* __restrict__ hi,
                           u16* __restrict__ lo, u16* __restrict__ thi)
{
    __shared__ float t[32][33];
    const long long z = blockIdx.z;
    const long long base = z * 1048576;
    const int r0 = blockIdx.y * 32, c0 = blockIdx.x * 32;
    for (int j = threadIdx.y; j < 32; j += 8) {
        const float v = q[base + (long long)(r0 + j) * 1024 + c0 + threadIdx.x];
        t[j][threadIdx.x] = v;
        const long long o = base + (long long)(r0 + j) * 1024 + c0 + threadIdx.x;
        const u16 h = f2h(v);
        hi[o] = h;
        lo[o] = f2h(v - h2f(h));
    }
    __syncthreads();
    for (int j = threadIdx.y; j < 32; j += 8)
        thi[base + (long long)(c0 + j) * 1024 + r0 + threadIdx.x] = f2h(t[threadIdx.x][j]);
}

// Wt[c][r] = W[r][c], fp16 single (W pre-pass; W rounding error negligible)
__global__ void transpose_cvt_w(const float* __restrict__ in, u16* __restrict__ hi)
{
    __shared__ float t[32][33];
    const int r0 = blockIdx.y * 32, c0 = blockIdx.x * 32;
    for (int j = threadIdx.y; j < 32; j += 8)
        t[j][threadIdx.x] = in[(long long)(r0 + j) * 1024 + c0 + threadIdx.x];
    __syncthreads();
    for (int j = threadIdx.y; j < 32; j += 8)
        hi[(long long)(c0 + j) * 1024 + r0 + threadIdx.x] = f2h(t[threadIdx.x][j]);
}

// row softmax (fp32 in, fp16 out), one 256-thread block per 1024-elem row
__global__ void softmax_f16(const float* __restrict__ S, u16* __restrict__ A)
{
    const long long row = blockIdx.x;
    const float* r = S + row * (long long)LQ_N;
    const int t = threadIdx.x;
    float4 v = ((const float4*)r)[t];

    float m = fmaxf(fmaxf(v.x, v.y), fmaxf(v.z, v.w));
#pragma unroll
    for (int off = 32; off > 0; off >>= 1)
        m = fmaxf(m, __shfl_xor(m, off));

    __shared__ float red[4];
    const int lane = t & 63, wid = t >> 6;
    if (lane == 0) red[wid] = m;
    __syncthreads();
    m = fmaxf(fmaxf(red[0], red[1]), fmaxf(red[2], red[3]));
    __syncthreads();

    v.x = __expf(v.x - m); v.y = __expf(v.y - m);
    v.z = __expf(v.z - m); v.w = __expf(v.w - m);
    float s = v.x + v.y + v.z + v.w;
#pragma unroll
    for (int off = 32; off > 0; off >>= 1)
        s += __shfl_xor(s, off);
    if (lane == 0) red[wid] = s;
    __syncthreads();
    s = red[0] + red[1] + red[2] + red[3];

    const float inv = 1.0f / s;
    ushort4 o;
    o.x = f2h(v.x * inv); o.y = f2h(v.y * inv);
    o.z = f2h(v.z * inv); o.w = f2h(v.w * inv);
    ((ushort4*)(A + row * (long long)LQ_N))[t] = o;
}

// ---------------------------------------------------------------------------
// Fallback fp32 path (round-1, verified; needs only 128 MB ws)
// ---------------------------------------------------------------------------
#define BM 128
#define BN 128
#define BK 8
#define TM 8
#define TN 8

template<bool TRANSB, bool BIAS, bool RELU>
__launch_bounds__(256)
__global__ void gemm_k(const float* __restrict__ A, const float* __restrict__ Bmat,
                       const float* __restrict__ bias, float* __restrict__ C,
                       int M, int N, int K,
                       long long sA, long long sB, long long sC)
{
    __shared__ float As[BK][BM];
    __shared__ float Bs[BK][BN];
    const int tid = threadIdx.x;
    const int tx = tid & 15;
    const int ty = tid >> 4;
    const int bn = blockIdx.x * BN;
    const int bm = blockIdx.y * BM;
    const long long z = blockIdx.z;
    A += z * sA; Bmat += z * sB; C += z * sC;
    float acc[TM][TN];
#pragma unroll
    for (int i = 0; i < TM; i++)
#pragma unroll
        for (int j = 0; j < TN; j++) acc[i][j] = 0.f;
    const int arow = tid >> 1;
    const int acol = (tid & 1) * 4;
    const int bk_n = tid >> 5;
    const int bn_n = (tid & 31) * 4;
    for (int k0 = 0; k0 < K; k0 += BK) {
        float4 a4 = *(const float4*)&A[(long long)(bm + arow) * K + k0 + acol];
        As[acol + 0][arow] = a4.x; As[acol + 1][arow] = a4.y;
        As[acol + 2][arow] = a4.z; As[acol + 3][arow] = a4.w;
        if (TRANSB) {
            float4 b4 = *(const float4*)&Bmat[(long long)(bn + arow) * K + k0 + acol];
            Bs[acol + 0][arow] = b4.x; Bs[acol + 1][arow] = b4.y;
            Bs[acol + 2][arow] = b4.z; Bs[acol + 3][arow] = b4.w;
        } else {
            float4 b4 = *(const float4*)&Bmat[(long long)(k0 + bk_n) * N + bn + bn_n];
            *(float4*)&Bs[bk_n][bn_n] = b4;
        }
        __syncthreads();
#pragma unroll
        for (int k = 0; k < BK; k++) {
            float a[TM], b[TN];
            *(float4*)&a[0] = *(const float4*)&As[k][ty * TM];
            *(float4*)&a[4] = *(const float4*)&As[k][ty * TM + 4];
            *(float4*)&b[0] = *(const float4*)&Bs[k][tx * TN];
            *(float4*)&b[4] = *(const float4*)&Bs[k][tx * TN + 4];
#pragma unroll
            for (int i = 0; i < TM; i++)
#pragma unroll
                for (int j = 0; j < TN; j++)
                    acc[i][j] = fmaf(a[i], b[j], acc[i][j]);
        }
        __syncthreads();
    }
#pragma unroll
    for (int i = 0; i < TM; i++) {
        const int row = bm + ty * TM + i;
#pragma unroll
        for (int j = 0; j < TN; j += 4) {
            const int col = bn + tx * TN + j;
            float4 v;
            v.x = acc[i][j + 0]; v.y = acc[i][j + 1];
            v.z = acc[i][j + 2]; v.w = acc[i][j + 3];
            if (BIAS) {
                v.x += bias[col + 0]; v.y += bias[col + 1];
                v.z += bias[col + 2]; v.w += bias[col + 3];
            }
            if (RELU) {
                v.x = fmaxf(v.x, 0.f); v.y = fmaxf(v.y, 0.f);
                v.z = fmaxf(v.z, 0.f); v.w = fmaxf(v.w, 0.f);
            }
            *(float4*)&C[(long long)row * N + col] = v;
        }
    }
}

__global__ void softmax_k(float* __restrict__ S)
{
    const long long row = blockIdx.x;
    float* r = S + row * (long long)LQ_N;
    const int t = threadIdx.x;
    float4 v = ((float4*)r)[t];
    float m = fmaxf(fmaxf(v.x, v.y), fmaxf(v.z, v.w));
#pragma unroll
    for (int off = 32; off > 0; off >>= 1)
        m = fmaxf(m, __shfl_xor(m, off));
    __shared__ float red[4];
    const int lane = t & 63, wid = t >> 6;
    if (lane == 0) red[wid] = m;
    __syncthreads();
    m = fmaxf(fmaxf(red[0], red[1]), fmaxf(red[2], red[3]));
    __syncthreads();
    v.x = __expf(v.x - m); v.y = __expf(v.y - m);
    v.z = __expf(v.z - m); v.w = __expf(v.w - m);
    float s = v.x + v.y + v.z + v.w;
#pragma unroll
    for (int off = 32; off > 0; off >>= 1)
        s += __shfl_xor(s, off);
    if (lane == 0) red[wid] = s;
    __syncthreads();
    s = red[0] + red[1] + red[2] + red[3];
    const float inv = 1.0f / s;
    v.x *= inv; v.y *= inv; v.z *= inv; v.w *= inv;
    ((float4*)r)[t] = v;
}

extern "C" void kernel_launch(void* const* d_in, const int* in_sizes, int n_in,
                              void* d_out, int out_size, void* d_ws, size_t ws_size,
                              hipStream_t stream)
{
    const float* p    = (const float*)d_in[0];
    const float* q    = (const float*)d_in[1];
    const float* W    = (const float*)d_in[2];
    const float* bias = (const float*)d_in[3];
    float* out = (float*)d_out;

    const size_t MB32 = 33554432ull;                 // 16M fp16
    const size_t NEED = 5 * MB32 + 2097152ull;       // 160 MB + 2 MB

    if (ws_size >= NEED) {
        char* w = (char*)d_ws;
        u16* p16   = (u16*)(w + 0 * MB32);
        u16* q_hi  = (u16*)(w + 1 * MB32);
        u16* q_lo  = (u16*)(w + 2 * MB32);
        u16* keys  = (u16*)(w + 3 * MB32);
        u16* qT    = (u16*)(w + 4 * MB32);
        u16* Wt    = (u16*)(w + 5 * MB32);
        float* scores = (float*)(w + 1 * MB32);  // reuses q_hi/q_lo after GEMM1
        u16* attn     = (u16*)(w + 0 * MB32);    // reuses p16 after GEMM2

        const long long n4 = (long long)B_N * LQ_N * H_N / 4;
        cvt_f16<<<dim3((unsigned)(n4 / 256)), 256, 0, stream>>>(p, p16, n4);
        fuse_cvt_q<<<dim3(32, 32, B_N), dim3(32, 8), 0, stream>>>(q, q_hi, q_lo, qT);
        transpose_cvt_w<<<dim3(32, 32, 1), dim3(32, 8), 0, stream>>>(W, Wt);

        // keys = (q_hi + q_lo) @ Wt + b : BK32 split, 256x256, grid 256.
        gemm2t<32, true, 1><<<256, 512, 0, stream>>>(
            q_hi, q_lo, Wt, bias, nullptr, keys,
            H_N, /*gn=*/4, /*gmn=*/256, 0, 0, 0);

        // scores[b] = p16[b] @ keys[b]^T : BK64 dense, 256x256, grid 256.
        gemm2t<64, false, 0><<<256, 512, 0, stream>>>(
            p16, p16, keys, nullptr, scores, nullptr,
            LQ_N, /*gn=*/4, /*gmn=*/16,
            (long long)LP_N * H_N, (long long)LQ_N * H_N, (long long)LP_N * LQ_N);

        softmax_f16<<<B_N * LP_N, 256, 0, stream>>>(scores, attn);

        // out[b] = relu(attn[b] @ q[b]) : BK64 dense, 256x256, grid 256.
        gemm2t<64, false, 2><<<256, 512, 0, stream>>>(
            attn, attn, qT, nullptr, out, nullptr,
            H_N, /*gn=*/4, /*gmn=*/16,
            (long long)LP_N * LQ_N, (long long)H_N * LQ_N, (long long)LP_N * H_N);
    } else {
        float* keys   = (float*)d_ws;
        float* scores = keys + (long long)B_N * LQ_N * H_N;

        gemm_k<false, true, false><<<dim3(H_N / BN, (B_N * LQ_N) / BM, 1), 256, 0, stream>>>(
            q, W, bias, keys, B_N * LQ_N, H_N, H_N, 0, 0, 0);
        gemm_k<true, false, false><<<dim3(LQ_N / BN, LP_N / BM, B_N), 256, 0, stream>>>(
            p, keys, nullptr, scores, LP_N, LQ_N, H_N,
            (long long)LP_N * H_N, (long long)LQ_N * H_N, (long long)LP_N * LQ_N);
        softmax_k<<<B_N * LP_N, 256, 0, stream>>>(scores);
        gemm_k<false, false, true><<<dim3(H_N / BN, LP_N / BM, B_N), 256, 0, stream>>>(
            scores, q, nullptr, out, LP_N, H_N, LQ_N,
            (long long)LP_N * LQ_N, (long long)LQ_N * H_N, (long long)LP_N * H_N);
    }
}